// Round 8
// baseline (393.432 us; speedup 1.0000x reference)
//
#include <hip/hip_runtime.h>

#define DDIM    128
#define NNODES  50000
#define NEDGES  800000
#define NLAYERS 3
#define LN_EPS  1e-5f
#define NSCAN   ((NNODES + 255) / 256)
#define NSLICE  8
#define SLICESZ ((NNODES + NSLICE - 1) / NSLICE)              // 6250
#define FILL_EPT 8
#define FILL_CHUNK (256 * FILL_EPT)                           // 2048
#define FILL_NCHUNK ((NEDGES + FILL_CHUNK - 1) / FILL_CHUNK)  // 391

typedef short s16x8 __attribute__((ext_vector_type(8)));
typedef float f32x4 __attribute__((ext_vector_type(4)));
typedef unsigned int u32;

__device__ __forceinline__ unsigned short f2bf(float f) {
    union { float f; unsigned u; } c; c.f = f;
    unsigned r = c.u + 0x7fff + ((c.u >> 16) & 1);   // RNE
    return (unsigned short)(r >> 16);
}
__device__ __forceinline__ float bf2f_u(unsigned short h) {
    union { unsigned u; float f; } c; c.u = (unsigned)h << 16;
    return c.f;
}
__device__ __forceinline__ float bflo(u32 v) { return __uint_as_float(v << 16); }
__device__ __forceinline__ float bfhi(u32 v) { return __uint_as_float(v & 0xffff0000u); }

// ---------------------------------------------------------------------------
// CSR build
// ---------------------------------------------------------------------------
__global__ __launch_bounds__(256) void hist_kernel(
    const int* __restrict__ edge, int* __restrict__ deg)
{
    int e = blockIdx.x * 256 + threadIdx.x;
    if (e < NEDGES) atomicAdd(&deg[edge[NEDGES + e]], 1);
}

__global__ __launch_bounds__(256) void scan_part_kernel(
    const int* __restrict__ deg, int* __restrict__ offsets, int* __restrict__ partials)
{
    __shared__ int tmp[256];
    int t = threadIdx.x, i = blockIdx.x * 256 + t;
    int v = (i < NNODES) ? deg[i] : 0;
    tmp[t] = v; __syncthreads();
    for (int d = 1; d < 256; d <<= 1) {
        int add = (t >= d) ? tmp[t - d] : 0;
        __syncthreads();
        tmp[t] += add;
        __syncthreads();
    }
    if (i < NNODES) offsets[i + 1] = tmp[t];
    if (t == 255) partials[blockIdx.x] = tmp[255];
}

// merged: every block re-scans the 196 partials in LDS, adds its exclusive sum
__global__ __launch_bounds__(256) void scan_add_kernel(
    int* __restrict__ offsets, const int* __restrict__ partials)
{
    __shared__ int tmp[256];
    int t = threadIdx.x;
    int v = (t < NSCAN) ? partials[t] : 0;
    tmp[t] = v; __syncthreads();
    for (int d = 1; d < 256; d <<= 1) {
        int add = (t >= d) ? tmp[t - d] : 0;
        __syncthreads();
        tmp[t] += add;
        __syncthreads();
    }
    int bexcl = (blockIdx.x == 0) ? 0 : tmp[blockIdx.x - 1];
    int i = blockIdx.x * 256 + t;
    if (i < NNODES) offsets[i + 1] += bexcl;
    if (i == 0) offsets[0] = 0;
}

// XCD-sliced fill: block b -> dst slice (b&7), edge chunk (b>>3).
__global__ __launch_bounds__(256) void fill_kernel(
    const int* __restrict__ edge, const int* __restrict__ offsets,
    int* __restrict__ cursor, int* __restrict__ srcs)
{
    int slice = blockIdx.x & (NSLICE - 1);
    int chunk = blockIdx.x >> 3;
    int lo = slice * SLICESZ;
    int hi = lo + SLICESZ;
    int base = chunk * FILL_CHUNK + threadIdx.x;
    #pragma unroll
    for (int i = 0; i < FILL_EPT; ++i) {
        int e = base + i * 256;
        if (e < NEDGES) {
            int d = edge[NEDGES + e];
            if (d >= lo && d < hi) {
                int s = edge[e];
                int slot = atomicAdd(&cursor[d], 1);
                srcs[offsets[d] + slot] = s;
            }
        }
    }
}

// ---------------------------------------------------------------------------
// Wcat prepack: [Wl;Wr] fp32 -> bf16 in MFMA B-fragment order, per layer.
// ---------------------------------------------------------------------------
__global__ __launch_bounds__(256) void wpack_kernel(
    const float* __restrict__ Wl,
    const float* __restrict__ Wr,
    unsigned short* __restrict__ wpk)
{
    int idx = blockIdx.x * 256 + threadIdx.x;
    if (idx >= NLAYERS * 4096) return;
    int l   = idx >> 12;
    int rem = idx & 4095;
    int kt = rem >> 9, ct = (rem >> 6) & 7, ln = rem & 63;
    int k0 = kt * 32 + ((ln >> 4) << 3);
    int c  = ct * 16 + (ln & 15);
    const float* src = (kt < 4)
        ? Wl + (size_t)l * DDIM * DDIM + (size_t)k0 * DDIM + c
        : Wr + (size_t)l * DDIM * DDIM + (size_t)(k0 - 128) * DDIM + c;
    s16x8 o;
    #pragma unroll
    for (int j = 0; j < 8; ++j) o[j] = (short)f2bf(src[j * DDIM]);
    *(s16x8*)(wpk + (size_t)idx * 8) = o;
}

// ---------------------------------------------------------------------------
// K0: embed + LN -> xh0 (bf16)
// ---------------------------------------------------------------------------
__global__ __launch_bounds__(256) void embed_ln_kernel(
    const float* __restrict__ node_emb,
    const int* __restrict__ pos,
    const float* __restrict__ pos_table,
    const float* __restrict__ g,
    const float* __restrict__ b,
    u32* __restrict__ xh32)
{
    int wid  = (blockIdx.x * blockDim.x + threadIdx.x) >> 6;
    int lane = threadIdx.x & 63;
    if (wid >= NNODES) return;

    const float scale = 11.313708498984761f;  // sqrt(128)
    int p = pos[wid];

    float2 ne = *(const float2*)(node_emb + (size_t)wid * DDIM + lane * 2);
    float2 pt = *(const float2*)(pos_table + (size_t)p * DDIM + lane * 2);
    float v0 = ne.x * scale + pt.x;
    float v1 = ne.y * scale + pt.y;

    float s  = v0 + v1;
    float s2 = v0 * v0 + v1 * v1;
    #pragma unroll
    for (int m = 32; m > 0; m >>= 1) {
        s  += __shfl_xor(s,  m, 64);
        s2 += __shfl_xor(s2, m, 64);
    }
    float mean = s * (1.0f / DDIM);
    float var  = s2 * (1.0f / DDIM) - mean * mean;
    float rstd = rsqrtf(var + LN_EPS);

    float2 gv = *(const float2*)(g + lane * 2);
    float2 bv = *(const float2*)(b + lane * 2);
    float y0 = (v0 - mean) * rstd * gv.x + bv.x;
    float y1 = (v1 - mean) * rstd * gv.y + bv.y;
    xh32[(size_t)wid * 64 + lane] = (u32)f2bf(y0) | ((u32)f2bf(y1) << 16);
}

// ---------------------------------------------------------------------------
// K1: FUSED gather + SAGE MFMA layer.  256 thr / 4 waves; 64 nodes per block
// (wave owns 16 nodes).  Double-buffered xh: reads xh_in, writes xh_out.
//
// Phase 1 (per wave, node i=0..15): chunk-32 gather (8 row-loads in flight),
//   cross-q shfl reduce, pack to bf16, then 16 shfls distribute the row into
//   MFMA A-fragment registers of owner lanes (cl==i).  No LDS.
// Phase 2: A = [agg | xh_in] (K=256); B-frags streamed from global wpk
//   (64 KB, L2-resident, 1 KB/instr coalesced).  8x8 mfma_16x16x32_bf16.
// Phase 3: +bias, relu, +residual(xh_in), LN, store xh_out (+fp32 on last).
// ---------------------------------------------------------------------------
__global__ __launch_bounds__(256, 3) void sage_fused_kernel(
    const int* __restrict__ offsets,
    const int* __restrict__ srcs,
    const unsigned short* __restrict__ xh_in,
    unsigned short* __restrict__ xh_out,
    const unsigned short* __restrict__ wpk,   // this layer, B-frag order
    const float* __restrict__ bl,
    const float* __restrict__ g,
    const float* __restrict__ b,
    float* __restrict__ xout)                 // d_out on last layer, else null
{
    int t    = threadIdx.x;
    int wave = t >> 6;
    int lane = t & 63;
    int cl   = lane & 15;
    int q    = lane >> 4;
    int m0   = blockIdx.x * 64 + wave * 16;

    const uint4* xh4 = (const uint4*)xh_in;

    // ---- phase 1: gather 16 nodes into A-frag regs (agg half) ----
    uint4 af_agg[4];
    #pragma unroll 1
    for (int i = 0; i < 16; ++i) {
        int node = m0 + i;
        if (node >= NNODES) node = NNODES - 1;
        int beg = offsets[node];
        int end = offsets[node + 1];

        float ga[8];
        #pragma unroll
        for (int k = 0; k < 8; ++k) ga[k] = 0.0f;

        for (int j = beg; j < end; j += 32) {
            int sidx[8];
            #pragma unroll
            for (int c = 0; c < 8; ++c) {
                int jj = j + c * 4 + q;
                sidx[c] = (jj < end) ? srcs[jj] : -1;
            }
            uint4 u[8];
            #pragma unroll
            for (int c = 0; c < 8; ++c) {
                u[c] = make_uint4(0u, 0u, 0u, 0u);
                if (sidx[c] >= 0)
                    u[c] = xh4[(size_t)sidx[c] * 16 + cl];
            }
            #pragma unroll
            for (int c = 0; c < 8; ++c) {
                ga[0] += bflo(u[c].x); ga[1] += bfhi(u[c].x);
                ga[2] += bflo(u[c].y); ga[3] += bfhi(u[c].y);
                ga[4] += bflo(u[c].z); ga[5] += bfhi(u[c].z);
                ga[6] += bflo(u[c].w); ga[7] += bfhi(u[c].w);
            }
        }
        #pragma unroll
        for (int k = 0; k < 8; ++k) {
            ga[k] += __shfl_xor(ga[k], 16, 64);
            ga[k] += __shfl_xor(ga[k], 32, 64);
        }
        uint4 o;
        o.x = (u32)f2bf(ga[0]) | ((u32)f2bf(ga[1]) << 16);
        o.y = (u32)f2bf(ga[2]) | ((u32)f2bf(ga[3]) << 16);
        o.z = (u32)f2bf(ga[4]) | ((u32)f2bf(ga[5]) << 16);
        o.w = (u32)f2bf(ga[6]) | ((u32)f2bf(ga[7]) << 16);

        // distribute: owner lane (q,cl==i) takes chunk kt*4+q from lane kt*4+q
        #pragma unroll
        for (int kt = 0; kt < 4; ++kt) {
            int src = kt * 4 + q;
            u32 a0 = __shfl(o.x, src, 64);
            u32 a1 = __shfl(o.y, src, 64);
            u32 a2 = __shfl(o.z, src, 64);
            u32 a3 = __shfl(o.w, src, 64);
            if (cl == i) af_agg[kt] = make_uint4(a0, a1, a2, a3);
        }
    }

    // ---- phase 2: MFMA ----
    int m  = m0 + cl;
    int mc = (m < NNODES) ? m : (NNODES - 1);

    s16x8 af[8];
    #pragma unroll
    for (int kt = 0; kt < 4; ++kt) {
        uint4 v = af_agg[kt];
        af[kt] = *(s16x8*)&v;
    }
    #pragma unroll
    for (int kt = 4; kt < 8; ++kt)
        af[kt] = *(const s16x8*)(xh_in + (size_t)mc * DDIM + (kt - 4) * 32 + q * 8);

    f32x4 acc[8];
    #pragma unroll
    for (int ct = 0; ct < 8; ++ct) acc[ct] = (f32x4){0.f, 0.f, 0.f, 0.f};

    const s16x8* wp = (const s16x8*)wpk;
    #pragma unroll
    for (int kt = 0; kt < 8; ++kt) {
        #pragma unroll
        for (int ct = 0; ct < 8; ++ct) {
            s16x8 bfr = wp[(size_t)(((kt << 3) + ct) << 6) + lane];
            acc[ct] = __builtin_amdgcn_mfma_f32_16x16x32_bf16(af[kt], bfr, acc[ct], 0, 0, 0);
        }
    }

    // ---- phase 3: epilogue (C layout: col = ct*16+cl, node = m0 + q*4 + r) --
    float bias[8], gg[8], bb[8];
    #pragma unroll
    for (int ct = 0; ct < 8; ++ct) {
        int c = ct * 16 + cl;
        bias[ct] = bl[c]; gg[ct] = g[c]; bb[ct] = b[c];
    }

    float hbuf[8][4];
    #pragma unroll
    for (int ct = 0; ct < 8; ++ct) {
        #pragma unroll
        for (int r = 0; r < 4; ++r) {
            int node = m0 + q * 4 + r;
            int nc   = (node < NNODES) ? node : (NNODES - 1);
            float hv = fmaxf(acc[ct][r] + bias[ct], 0.0f);
            hbuf[ct][r] = hv + bf2f_u(xh_in[(size_t)nc * DDIM + ct * 16 + cl]);
        }
    }

    float s[4], s2[4];
    #pragma unroll
    for (int r = 0; r < 4; ++r) {
        float a0 = 0.f, a1 = 0.f;
        #pragma unroll
        for (int ct = 0; ct < 8; ++ct) {
            a0 += hbuf[ct][r];
            a1 += hbuf[ct][r] * hbuf[ct][r];
        }
        #pragma unroll
        for (int msk = 1; msk < 16; msk <<= 1) {
            a0 += __shfl_xor(a0, msk, 64);
            a1 += __shfl_xor(a1, msk, 64);
        }
        s[r] = a0; s2[r] = a1;
    }

    #pragma unroll
    for (int r = 0; r < 4; ++r) {
        int node = m0 + q * 4 + r;
        if (node >= NNODES) continue;
        float mean = s[r] * (1.0f / DDIM);
        float var  = s2[r] * (1.0f / DDIM) - mean * mean;
        float rstd = rsqrtf(var + LN_EPS);
        #pragma unroll
        for (int ct = 0; ct < 8; ++ct) {
            float y = (hbuf[ct][r] - mean) * rstd * gg[ct] + bb[ct];
            size_t off = (size_t)node * DDIM + ct * 16 + cl;
            xh_out[off] = f2bf(y);
            if (xout) xout[off] = y;
        }
    }
}

// ---------------------------------------------------------------------------
extern "C" void kernel_launch(void* const* d_in, const int* in_sizes, int n_in,
                              void* d_out, int out_size, void* d_ws, size_t ws_size,
                              hipStream_t stream)
{
    const float* node_emb = (const float*)d_in[0];
    const int*   pos      = (const int*)d_in[1];
    const int*   edge     = (const int*)d_in[2];
    const float* pos_tab  = (const float*)d_in[3];
    const float* Wl       = (const float*)d_in[4];
    const float* bl       = (const float*)d_in[5];
    const float* Wr       = (const float*)d_in[6];
    const float* eg       = (const float*)d_in[7];
    const float* eb       = (const float*)d_in[8];
    const float* hg       = (const float*)d_in[9];
    const float* hb       = (const float*)d_in[10];

    // workspace: [xh0 bf16][xh1 bf16][wpk bf16][CSR ints]
    unsigned short* xh0 = (unsigned short*)d_ws;
    unsigned short* xh1 = xh0 + (size_t)NNODES * DDIM;
    unsigned short* wpk = xh1 + (size_t)NNODES * DDIM;
    int* deg      = (int*)(wpk + (size_t)NLAYERS * 4096 * 8);
    int* cursor   = deg + NNODES;
    int* offsets  = cursor + NNODES;
    int* partials = offsets + NNODES + 2;
    int* srcs     = partials + 256;

    // ---- CSR build (edges constant across layers) ----
    hipMemsetAsync(deg, 0, 2 * NNODES * sizeof(int), stream);
    hist_kernel<<<(NEDGES + 255) / 256, 256, 0, stream>>>(edge, deg);
    scan_part_kernel<<<NSCAN, 256, 0, stream>>>(deg, offsets, partials);
    scan_add_kernel<<<NSCAN, 256, 0, stream>>>(offsets, partials);
    fill_kernel<<<FILL_NCHUNK * NSLICE, 256, 0, stream>>>(edge, offsets, cursor, srcs);

    // ---- W prepack (all layers) ----
    wpack_kernel<<<(NLAYERS * 4096 + 255) / 256, 256, 0, stream>>>(Wl, Wr, wpk);

    // ---- embed + LN ----
    embed_ln_kernel<<<(NNODES * 64 + 255) / 256, 256, 0, stream>>>(
        node_emb, pos, pos_tab, eg, eb, (u32*)xh0);

    // ---- fused layers (ping-pong xh) ----
    unsigned short* xin  = xh0;
    unsigned short* xout = xh1;
    for (int l = 0; l < NLAYERS; ++l) {
        sage_fused_kernel<<<(NNODES + 63) / 64, 256, 0, stream>>>(
            offsets, srcs, xin, xout,
            wpk + (size_t)l * 4096 * 8,
            bl + (size_t)l * DDIM,
            hg + (size_t)l * DDIM,
            hb + (size_t)l * DDIM,
            (l == NLAYERS - 1) ? (float*)d_out : (float*)nullptr);
        unsigned short* tmp = xin; xin = xout; xout = tmp;
    }
}

// Round 9
// 327.717 us; speedup vs baseline: 1.2005x; 1.2005x over previous
//
#include <hip/hip_runtime.h>

#define DDIM    128
#define NNODES  50000
#define NEDGES  800000
#define NLAYERS 3
#define LN_EPS  1e-5f
#define NSCAN   ((NNODES + 255) / 256)
#define NSLICE  8
#define SLICESZ ((NNODES + NSLICE - 1) / NSLICE)              // 6250
#define FILL_EPT 8
#define FILL_CHUNK (256 * FILL_EPT)                           // 2048
#define FILL_NCHUNK ((NEDGES + FILL_CHUNK - 1) / FILL_CHUNK)  // 391

#define HISTB  ((NEDGES + 255) / 256)                         // 3125
#define WPACKB ((NLAYERS * 4096 + 255) / 256)                 // 48
#define EMBEDB ((NNODES * 64 + 255) / 256)                    // 12500

typedef short s16x8 __attribute__((ext_vector_type(8)));
typedef float f32x4 __attribute__((ext_vector_type(4)));
typedef unsigned int u32;

__device__ __forceinline__ unsigned short f2bf(float f) {
    union { float f; unsigned u; } c; c.f = f;
    unsigned r = c.u + 0x7fff + ((c.u >> 16) & 1);   // RNE
    return (unsigned short)(r >> 16);
}
__device__ __forceinline__ float bf2f_u(unsigned short h) {
    union { unsigned u; float f; } c; c.u = (unsigned)h << 16;
    return c.f;
}
__device__ __forceinline__ float bflo(u32 v) { return __uint_as_float(v << 16); }
__device__ __forceinline__ float bfhi(u32 v) { return __uint_as_float(v & 0xffff0000u); }

// ---------------------------------------------------------------------------
// PREP: hist + wpack + embed_ln merged (mutually independent work)
//   blocks [0, HISTB)                : deg histogram
//   blocks [HISTB, HISTB+WPACKB)     : W prepack (fp32 -> bf16 B-frag order)
//   blocks [HISTB+WPACKB, ...EMBEDB) : embed + LN -> xh bf16
// ---------------------------------------------------------------------------
__global__ __launch_bounds__(256) void prep_kernel(
    const int* __restrict__ edge, int* __restrict__ deg,
    const float* __restrict__ Wl, const float* __restrict__ Wr,
    unsigned short* __restrict__ wpk,
    const float* __restrict__ node_emb, const int* __restrict__ pos,
    const float* __restrict__ pos_table,
    const float* __restrict__ eg, const float* __restrict__ eb,
    u32* __restrict__ xh32)
{
    int t = threadIdx.x;

    if (blockIdx.x < HISTB) {
        // ---- hist ----
        int e = blockIdx.x * 256 + t;
        if (e < NEDGES) atomicAdd(&deg[edge[NEDGES + e]], 1);
        return;
    }

    if (blockIdx.x < HISTB + WPACKB) {
        // ---- wpack ----
        int idx = (blockIdx.x - HISTB) * 256 + t;
        if (idx >= NLAYERS * 4096) return;
        int l   = idx >> 12;
        int rem = idx & 4095;
        int kt = rem >> 9, ct = (rem >> 6) & 7, ln = rem & 63;
        int k0 = kt * 32 + ((ln >> 4) << 3);
        int c  = ct * 16 + (ln & 15);
        const float* src = (kt < 4)
            ? Wl + (size_t)l * DDIM * DDIM + (size_t)k0 * DDIM + c
            : Wr + (size_t)l * DDIM * DDIM + (size_t)(k0 - 128) * DDIM + c;
        s16x8 o;
        #pragma unroll
        for (int j = 0; j < 8; ++j) o[j] = (short)f2bf(src[j * DDIM]);
        *(s16x8*)(wpk + (size_t)idx * 8) = o;
        return;
    }

    // ---- embed + LN ----
    int wid  = ((blockIdx.x - HISTB - WPACKB) * 256 + t) >> 6;
    int lane = t & 63;
    if (wid >= NNODES) return;

    const float scale = 11.313708498984761f;  // sqrt(128)
    int p = pos[wid];

    float2 ne = *(const float2*)(node_emb + (size_t)wid * DDIM + lane * 2);
    float2 pt = *(const float2*)(pos_table + (size_t)p * DDIM + lane * 2);
    float v0 = ne.x * scale + pt.x;
    float v1 = ne.y * scale + pt.y;

    float s  = v0 + v1;
    float s2 = v0 * v0 + v1 * v1;
    #pragma unroll
    for (int m = 32; m > 0; m >>= 1) {
        s  += __shfl_xor(s,  m, 64);
        s2 += __shfl_xor(s2, m, 64);
    }
    float mean = s * (1.0f / DDIM);
    float var  = s2 * (1.0f / DDIM) - mean * mean;
    float rstd = rsqrtf(var + LN_EPS);

    float2 gv = *(const float2*)(eg + lane * 2);
    float2 bv = *(const float2*)(eb + lane * 2);
    float y0 = (v0 - mean) * rstd * gv.x + bv.x;
    float y1 = (v1 - mean) * rstd * gv.y + bv.y;
    xh32[(size_t)wid * 64 + lane] = (u32)f2bf(y0) | ((u32)f2bf(y1) << 16);
}

// ---------------------------------------------------------------------------
// CSR scan (2 kernels) + XCD-sliced fill
// ---------------------------------------------------------------------------
__global__ __launch_bounds__(256) void scan_part_kernel(
    const int* __restrict__ deg, int* __restrict__ offsets, int* __restrict__ partials)
{
    __shared__ int tmp[256];
    int t = threadIdx.x, i = blockIdx.x * 256 + t;
    int v = (i < NNODES) ? deg[i] : 0;
    tmp[t] = v; __syncthreads();
    for (int d = 1; d < 256; d <<= 1) {
        int add = (t >= d) ? tmp[t - d] : 0;
        __syncthreads();
        tmp[t] += add;
        __syncthreads();
    }
    if (i < NNODES) offsets[i + 1] = tmp[t];
    if (t == 255) partials[blockIdx.x] = tmp[255];
}

__global__ __launch_bounds__(256) void scan_add_kernel(
    int* __restrict__ offsets, const int* __restrict__ partials)
{
    __shared__ int tmp[256];
    int t = threadIdx.x;
    int v = (t < NSCAN) ? partials[t] : 0;
    tmp[t] = v; __syncthreads();
    for (int d = 1; d < 256; d <<= 1) {
        int add = (t >= d) ? tmp[t - d] : 0;
        __syncthreads();
        tmp[t] += add;
        __syncthreads();
    }
    int bexcl = (blockIdx.x == 0) ? 0 : tmp[blockIdx.x - 1];
    int i = blockIdx.x * 256 + t;
    if (i < NNODES) offsets[i + 1] += bexcl;
    if (i == 0) offsets[0] = 0;
}

__global__ __launch_bounds__(256) void fill_kernel(
    const int* __restrict__ edge, const int* __restrict__ offsets,
    int* __restrict__ cursor, int* __restrict__ srcs)
{
    int slice = blockIdx.x & (NSLICE - 1);
    int chunk = blockIdx.x >> 3;
    int lo = slice * SLICESZ;
    int hi = lo + SLICESZ;
    int base = chunk * FILL_CHUNK + threadIdx.x;
    #pragma unroll
    for (int i = 0; i < FILL_EPT; ++i) {
        int e = base + i * 256;
        if (e < NEDGES) {
            int d = edge[NEDGES + e];
            if (d >= lo && d < hi) {
                int s = edge[e];
                int slot = atomicAdd(&cursor[d], 1);
                srcs[offsets[d] + slot] = s;
            }
        }
    }
}

// ---------------------------------------------------------------------------
// K1: gather, chunk-32 MLP: wave per node; lane (q,cl); 8 row-loads in flight.
// ---------------------------------------------------------------------------
__global__ __launch_bounds__(256) void gather_kernel(
    const int* __restrict__ offsets,
    const int* __restrict__ srcs,
    const uint4* __restrict__ xh4,     // row = 16 uint4
    uint4* __restrict__ agg4)
{
    int wid  = (blockIdx.x * 256 + threadIdx.x) >> 6;
    int lane = threadIdx.x & 63;
    if (wid >= NNODES) return;
    int q = lane >> 4, cl = lane & 15;

    int beg = offsets[wid];
    int end = offsets[wid + 1];

    float acc[8];
    #pragma unroll
    for (int k = 0; k < 8; ++k) acc[k] = 0.0f;

    for (int j = beg; j < end; j += 32) {
        int sidx[8];
        #pragma unroll
        for (int c = 0; c < 8; ++c) {
            int jj = j + c * 4 + q;
            sidx[c] = (jj < end) ? srcs[jj] : -1;
        }
        uint4 u[8];
        #pragma unroll
        for (int c = 0; c < 8; ++c) {
            u[c] = make_uint4(0u, 0u, 0u, 0u);
            if (sidx[c] >= 0)
                u[c] = xh4[(size_t)sidx[c] * 16 + cl];
        }
        #pragma unroll
        for (int c = 0; c < 8; ++c) {
            acc[0] += bflo(u[c].x); acc[1] += bfhi(u[c].x);
            acc[2] += bflo(u[c].y); acc[3] += bfhi(u[c].y);
            acc[4] += bflo(u[c].z); acc[5] += bfhi(u[c].z);
            acc[6] += bflo(u[c].w); acc[7] += bfhi(u[c].w);
        }
    }

    #pragma unroll
    for (int k = 0; k < 8; ++k) {
        acc[k] += __shfl_xor(acc[k], 16, 64);
        acc[k] += __shfl_xor(acc[k], 32, 64);
    }

    if (q == 0) {
        uint4 o;
        o.x = (u32)f2bf(acc[0]) | ((u32)f2bf(acc[1]) << 16);
        o.y = (u32)f2bf(acc[2]) | ((u32)f2bf(acc[3]) << 16);
        o.z = (u32)f2bf(acc[4]) | ((u32)f2bf(acc[5]) << 16);
        o.w = (u32)f2bf(acc[6]) | ((u32)f2bf(acc[7]) << 16);
        agg4[(size_t)wid * 16 + cl] = o;
    }
}

// ---------------------------------------------------------------------------
// K2: MFMA sage layer (R7-proven). 64 nodes/block, W prestaged to LDS.
// ---------------------------------------------------------------------------
__global__ __launch_bounds__(256) void sage_mfma_kernel(
    const unsigned short* __restrict__ agg,   // bf16 [N][128]
    unsigned short* __restrict__ xh,          // bf16 [N][128], in/out
    const unsigned short* __restrict__ wpk,   // this layer, B-frag order
    const float* __restrict__ bl,
    const float* __restrict__ g,
    const float* __restrict__ b,
    float* __restrict__ xout)                 // d_out on last layer, else null
{
    __shared__ unsigned short wlds[4096 * 8];   // 64 KB

    int t    = threadIdx.x;
    int wave = t >> 6;
    int lane = t & 63;
    int cl   = lane & 15;
    int q    = lane >> 4;

    {
        const s16x8* srcv = (const s16x8*)wpk;
        s16x8* dstv = (s16x8*)wlds;
        for (int i = t; i < 4096; i += 256) dstv[i] = srcv[i];
    }
    __syncthreads();

    float bias[8], gg[8], bb[8];
    #pragma unroll
    for (int ct = 0; ct < 8; ++ct) {
        int c = ct * 16 + cl;
        bias[ct] = bl[c]; gg[ct] = g[c]; bb[ct] = b[c];
    }

    int m0 = blockIdx.x * 64 + wave * 16;
    int m  = m0 + cl;
    int mc = (m < NNODES) ? m : (NNODES - 1);

    s16x8 af[8];
    #pragma unroll
    for (int kt = 0; kt < 4; ++kt)
        af[kt] = *(const s16x8*)(agg + (size_t)mc * DDIM + kt * 32 + q * 8);
    #pragma unroll
    for (int kt = 4; kt < 8; ++kt)
        af[kt] = *(const s16x8*)(xh + (size_t)mc * DDIM + (kt - 4) * 32 + q * 8);

    f32x4 acc[8];
    #pragma unroll
    for (int ct = 0; ct < 8; ++ct) acc[ct] = (f32x4){0.f, 0.f, 0.f, 0.f};

    #pragma unroll
    for (int kt = 0; kt < 8; ++kt) {
        #pragma unroll
        for (int ct = 0; ct < 8; ++ct) {
            s16x8 bfr = *(const s16x8*)&wlds[((((kt << 3) + ct) << 6) + lane) * 8];
            acc[ct] = __builtin_amdgcn_mfma_f32_16x16x32_bf16(af[kt], bfr, acc[ct], 0, 0, 0);
        }
    }

    float hbuf[8][4];
    #pragma unroll
    for (int ct = 0; ct < 8; ++ct) {
        #pragma unroll
        for (int r = 0; r < 4; ++r) {
            int node = m0 + q * 4 + r;
            int nc   = (node < NNODES) ? node : (NNODES - 1);
            float hv = fmaxf(acc[ct][r] + bias[ct], 0.0f);
            hbuf[ct][r] = hv + bf2f_u(xh[(size_t)nc * DDIM + ct * 16 + cl]);
        }
    }

    float s[4], s2[4];
    #pragma unroll
    for (int r = 0; r < 4; ++r) {
        float a0 = 0.f, a1 = 0.f;
        #pragma unroll
        for (int ct = 0; ct < 8; ++ct) {
            a0 += hbuf[ct][r];
            a1 += hbuf[ct][r] * hbuf[ct][r];
        }
        #pragma unroll
        for (int msk = 1; msk < 16; msk <<= 1) {
            a0 += __shfl_xor(a0, msk, 64);
            a1 += __shfl_xor(a1, msk, 64);
        }
        s[r] = a0; s2[r] = a1;
    }

    #pragma unroll
    for (int r = 0; r < 4; ++r) {
        int node = m0 + q * 4 + r;
        if (node >= NNODES) continue;
        float mean = s[r] * (1.0f / DDIM);
        float var  = s2[r] * (1.0f / DDIM) - mean * mean;
        float rstd = rsqrtf(var + LN_EPS);
        #pragma unroll
        for (int ct = 0; ct < 8; ++ct) {
            float y = (hbuf[ct][r] - mean) * rstd * gg[ct] + bb[ct];
            size_t off = (size_t)node * DDIM + ct * 16 + cl;
            xh[off] = f2bf(y);
            if (xout) xout[off] = y;
        }
    }
}

// ---------------------------------------------------------------------------
extern "C" void kernel_launch(void* const* d_in, const int* in_sizes, int n_in,
                              void* d_out, int out_size, void* d_ws, size_t ws_size,
                              hipStream_t stream)
{
    const float* node_emb = (const float*)d_in[0];
    const int*   pos      = (const int*)d_in[1];
    const int*   edge     = (const int*)d_in[2];
    const float* pos_tab  = (const float*)d_in[3];
    const float* Wl       = (const float*)d_in[4];
    const float* bl       = (const float*)d_in[5];
    const float* Wr       = (const float*)d_in[6];
    const float* eg       = (const float*)d_in[7];
    const float* eb       = (const float*)d_in[8];
    const float* hg       = (const float*)d_in[9];
    const float* hb       = (const float*)d_in[10];

    // workspace: [xh bf16][agg bf16][wpk bf16][CSR ints]
    unsigned short* xh  = (unsigned short*)d_ws;
    unsigned short* agg = xh + (size_t)NNODES * DDIM;
    unsigned short* wpk = agg + (size_t)NNODES * DDIM;
    int* deg      = (int*)(wpk + (size_t)NLAYERS * 4096 * 8);
    int* cursor   = deg + NNODES;
    int* offsets  = cursor + NNODES;
    int* partials = offsets + NNODES + 2;
    int* srcs     = partials + 256;

    // ---- prep: zero deg/cursor, then hist + wpack + embed in one dispatch --
    hipMemsetAsync(deg, 0, 2 * NNODES * sizeof(int), stream);
    prep_kernel<<<HISTB + WPACKB + EMBEDB, 256, 0, stream>>>(
        edge, deg, Wl, Wr, wpk, node_emb, pos, pos_tab, eg, eb, (u32*)xh);

    // ---- CSR scan + fill ----
    scan_part_kernel<<<NSCAN, 256, 0, stream>>>(deg, offsets, partials);
    scan_add_kernel<<<NSCAN, 256, 0, stream>>>(offsets, partials);
    fill_kernel<<<FILL_NCHUNK * NSLICE, 256, 0, stream>>>(edge, offsets, cursor, srcs);

    // ---- layers ----
    for (int l = 0; l < NLAYERS; ++l) {
        gather_kernel<<<(NNODES * 64 + 255) / 256, 256, 0, stream>>>(
            offsets, srcs, (const uint4*)xh, (uint4*)agg);

        sage_mfma_kernel<<<(NNODES + 63) / 64, 256, 0, stream>>>(
            agg, xh,
            wpk + (size_t)l * 4096 * 8,
            bl + (size_t)l * DDIM,
            hg + (size_t)l * DDIM,
            hb + (size_t)l * DDIM,
            (l == NLAYERS - 1) ? (float*)d_out : (float*)nullptr);
    }
}